// Round 7
// baseline (555.158 us; speedup 1.0000x reference)
//
#include <hip/hip_runtime.h>

// TripletAngularMarginLoss: bs=16384, d=64 (== number of classes)
// out = mean(relu(0.5 + ap - an)) + mean(relu(0.8-ap)) + mean(relu(an-0.4)) + CE
// ap[i] = min_{t[j]==t[i]} cos(x_i,x_j), an[i] = max_{t[j]!=t[i]} cos(x_i,x_j)
//
// R2: class-sort rows -> pure-negative fast path (1 max/entry).
// R6 post-mortem: LDS conflicts fixed (7.3M->0) yet mine unchanged 204->202us
//   -> R5's +110us was NOT the LDS layout. Prime suspect: fused finalize's
//   __threadfence() = buffer_wbl2 (full L2 writeback) per block on gfx950,
//   serialized per-XCD. R7: drop fence + fused finalize (separate tiny
//   kernel), revert mine to the no-LDS R4-class loop with a depth-2 register
//   prefetch pipeline (16-col groups).

#define N_ROWS 16384
#define N_DIM 64

typedef __attribute__((ext_vector_type(8))) short bf16x8;
typedef __attribute__((ext_vector_type(4))) float f32x4;

__device__ inline unsigned short f2bf(float f) {
  unsigned u = __float_as_uint(f);
  unsigned r = u + 0x7fffu + ((u >> 16) & 1u);   // round-to-nearest-even
  return (unsigned short)(r >> 16);
}

// order-preserving float->uint encoding for atomicMin/atomicMax
__device__ inline unsigned enc_key(float f) {
  unsigned u = __float_as_uint(f);
  return (u & 0x80000000u) ? ~u : (u | 0x80000000u);
}
__device__ inline float dec_key(unsigned k) {
  unsigned u = (k & 0x80000000u) ? (k ^ 0x80000000u) : ~k;
  return __uint_as_float(u);
}

// ---------------- K1: class histogram + min/max key init (64 blocks) --------
__global__ void hist_kernel(const int* __restrict__ tgt, int* __restrict__ hist,
                            unsigned* __restrict__ mp_key, unsigned* __restrict__ mn_key) {
  __shared__ int h[64];
  const int i = blockIdx.x * 256 + threadIdx.x;
  mp_key[i] = 0xFFFFFFFFu;                        // +inf key for min
  mn_key[i] = 0u;                                 // -inf key for max
  if (threadIdx.x < 64) h[threadIdx.x] = 0;
  __syncthreads();
  atomicAdd(&h[tgt[i]], 1);
  __syncthreads();
  if (threadIdx.x < 64 && h[threadIdx.x]) atomicAdd(&hist[threadIdx.x], h[threadIdx.x]);
}

// ---------------- K2: scan (per-block, redundant) + scatter + prep ----------
// 1024 blocks x 256 threads; block handles 16 rows (4 waves x 4 rows).
__global__ void prep_kernel(const float* __restrict__ x, const int* __restrict__ tgt,
                            const int* __restrict__ hist, int* __restrict__ cursor,
                            int* __restrict__ class_start,
                            unsigned short* __restrict__ xs, int* __restrict__ ts,
                            float* __restrict__ ce_row) {
  __shared__ int cs[64];
  const int tid  = threadIdx.x;
  const int lane = tid & 63;
  // exclusive prefix over the 64-class histogram (wave 0 only)
  if (tid < 64) {
    const int hv = hist[tid];
    int s = hv;
#pragma unroll
    for (int d = 1; d < 64; d <<= 1) {
      int t = __shfl_up(s, d, 64);
      if (tid >= d) s += t;
    }
    cs[tid] = s - hv;
    if (blockIdx.x == 0) {                 // publish for mine_kernel
      class_start[tid] = s - hv;
      if (tid == 63) class_start[64] = s;
    }
  }
  __syncthreads();

#pragma unroll
  for (int p = 0; p < 4; ++p) {
    const int r = blockIdx.x * 16 + (tid >> 6) * 4 + p;
    float v  = x[r * N_DIM + lane];
    float ss = v * v;
#pragma unroll
    for (int s = 1; s < 64; s <<= 1) ss += __shfl_xor(ss, s, 64);
    const float xn = v * rsqrtf(ss);

    // log-softmax CE contribution
    float mx = xn;
#pragma unroll
    for (int s = 1; s < 64; s <<= 1) mx = fmaxf(mx, __shfl_xor(mx, s, 64));
    float e  = __expf(xn - mx);
    float se = e;
#pragma unroll
    for (int s = 1; s < 64; s <<= 1) se += __shfl_xor(se, s, 64);
    const float lse = mx + __logf(se);
    const int   c   = tgt[r];                     // wave-uniform
    const float xt  = __shfl(xn, c, 64);

    int pos = 0;
    if (lane == 0) pos = cs[c] + atomicAdd(&cursor[c], 1);
    pos = __shfl(pos, 0, 64);
    xs[pos * N_DIM + lane] = f2bf(xn);
    if (lane == 0) { ts[pos] = c; ce_row[r] = lse - xt; }
  }
}

// ---------------- K3: MFMA similarity + hard mining (no LDS, no fence) ------
// grid = 64 iblk x 16 jspl = 1024 blocks of 256 threads (4 waves).
// Wave: 64 sorted i-rows register-resident (A), sweeps 1024 cols in 64
// 16-col groups with a depth-2 register prefetch pipeline.
__global__ void __launch_bounds__(256)
mine_kernel(const unsigned short* __restrict__ xs, const int* __restrict__ ts,
            const int* __restrict__ class_start,
            unsigned* __restrict__ mp_key, unsigned* __restrict__ mn_key) {
  const int lane    = threadIdx.x & 63;
  const int wv      = threadIdx.x >> 6;
  const int iblk    = blockIdx.x >> 4;
  const int jspl    = blockIdx.x & 15;
  const int rowbase = iblk * 256 + wv * 64;
  const int jbase   = jspl * 1024;
  const int m = lane & 15, q = lane >> 4;

  // A fragments: lane holds row (rowbase+tr*16+m), k-chunks q and q+4
  bf16x8 a[4][2];
#pragma unroll
  for (int tr = 0; tr < 4; ++tr) {
    const unsigned short* p = xs + (rowbase + tr * 16 + m) * N_DIM + q * 8;
    a[tr][0] = *(const bf16x8*)(p);
    a[tr][1] = *(const bf16x8*)(p + 32);
  }
  // classes of this lane's C/D rows (row = tr*16 + q*4 + r), packed 8b x 4
  int tpack[4];
#pragma unroll
  for (int tr = 0; tr < 4; ++tr) {
    int v = 0;
#pragma unroll
    for (int r = 0; r < 4; ++r)
      v |= ts[rowbase + tr * 16 + q * 4 + r] << (8 * r);
    tpack[tr] = v;
  }

  // positive-column interval for ALL rows of this wave (rows sorted by class)
  const int lo = class_start[ts[rowbase]];
  const int hi = class_start[ts[rowbase + 63] + 1];

  float mp[16], mn[16];
#pragma unroll
  for (int k = 0; k < 16; ++k) { mp[k] = __builtin_inff(); mn[k] = -__builtin_inff(); }
  const f32x4 fz = {0.f, 0.f, 0.f, 0.f};

  const int loff = m * N_DIM + q * 8;              // per-lane offset (shorts)
  const unsigned short* const pw = xs + jbase * N_DIM + loff;

  // depth-2 prefetch pipeline: stage s=g&1 holds fragments for group g
  bf16x8 pb0[2], pb1[2];
  pb0[0] = *(const bf16x8*)(pw);
  pb1[0] = *(const bf16x8*)(pw + 32);
  pb0[1] = *(const bf16x8*)(pw + 16 * N_DIM);
  pb1[1] = *(const bf16x8*)(pw + 16 * N_DIM + 32);

  for (int g = 0; g < 64; ++g) {
    const int s = g & 1;
    const bf16x8 cb0 = pb0[s], cb1 = pb1[s];
    if (g + 2 < 64) {                              // issue loads for group g+2
      const unsigned short* np = pw + (g + 2) * (16 * N_DIM);
      pb0[s] = *(const bf16x8*)(np);
      pb1[s] = *(const bf16x8*)(np + 32);
    }
    const int jb = jbase + g * 16;
    if (__builtin_expect((jb < hi) && (jb + 16 > lo), 0)) {  // slow path (rare)
      const int ctj = ts[jb + m];
#pragma unroll
      for (int tr = 0; tr < 4; ++tr) {
        f32x4 acc = __builtin_amdgcn_mfma_f32_16x16x32_bf16(a[tr][0], cb0, fz, 0, 0, 0);
        acc = __builtin_amdgcn_mfma_f32_16x16x32_bf16(a[tr][1], cb1, acc, 0, 0, 0);
#pragma unroll
        for (int r = 0; r < 4; ++r) {
          const bool  pos = (ctj == ((tpack[tr] >> (8 * r)) & 0xff));
          const float d   = acc[r];
          mp[tr * 4 + r] = fminf(mp[tr * 4 + r], pos ? d : __builtin_inff());
          mn[tr * 4 + r] = fmaxf(mn[tr * 4 + r], pos ? -__builtin_inff() : d);
        }
      }
    } else {                                       // pure-negative fast path
#pragma unroll
      for (int tr = 0; tr < 4; ++tr) {
        f32x4 acc = __builtin_amdgcn_mfma_f32_16x16x32_bf16(a[tr][0], cb0, fz, 0, 0, 0);
        acc = __builtin_amdgcn_mfma_f32_16x16x32_bf16(a[tr][1], cb1, acc, 0, 0, 0);
#pragma unroll
        for (int r = 0; r < 4; ++r)
          mn[tr * 4 + r] = fmaxf(mn[tr * 4 + r], acc[r]);
      }
    }
  }

  // reduce across the 16 m-lanes inside each q-group
#pragma unroll
  for (int s = 1; s < 16; s <<= 1) {
#pragma unroll
    for (int k = 0; k < 16; ++k) {
      mp[k] = fminf(mp[k], __shfl_xor(mp[k], s, 64));
      mn[k] = fmaxf(mn[k], __shfl_xor(mn[k], s, 64));
    }
  }
  if (m == 0) {
#pragma unroll
    for (int tr = 0; tr < 4; ++tr)
#pragma unroll
      for (int r = 0; r < 4; ++r) {
        const int row = rowbase + tr * 16 + q * 4 + r;
        atomicMin(&mp_key[row], enc_key(mp[tr * 4 + r]));
        atomicMax(&mn_key[row], enc_key(mn[tr * 4 + r]));
      }
  }
}

// ---------------- K4: final reduction (1 block, 1024 threads) ---------------
__global__ void finalize_kernel(const unsigned* __restrict__ mp_key, const unsigned* __restrict__ mn_key,
                                const float* __restrict__ ce_row, float* __restrict__ out) {
  __shared__ float red[16];
  float s1 = 0.f;
  for (int r = threadIdx.x; r < N_ROWS; r += 1024) {
    const float ap = dec_key(mp_key[r]);
    const float an = dec_key(mn_key[r]);
    s1 += fmaxf(0.5f + ap - an, 0.f) + fmaxf(0.8f - ap, 0.f) + fmaxf(an - 0.4f, 0.f)
        + ce_row[r];
  }
#pragma unroll
  for (int d = 1; d < 64; d <<= 1) s1 += __shfl_xor(s1, d, 64);
  const int wv = threadIdx.x >> 6;
  if ((threadIdx.x & 63) == 0) red[wv] = s1;
  __syncthreads();
  if (threadIdx.x == 0) {
    float t = 0.f;
#pragma unroll
    for (int w = 0; w < 16; ++w) t += red[w];
    out[0] = t * (1.0f / N_ROWS);
  }
}

extern "C" void kernel_launch(void* const* d_in, const int* in_sizes, int n_in,
                              void* d_out, int out_size, void* d_ws, size_t ws_size,
                              hipStream_t stream) {
  const float* x   = (const float*)d_in[0];
  const int*   tgt = (const int*)d_in[1];
  char* ws = (char*)d_ws;

  unsigned short* xs     = (unsigned short*)ws;                           // 2 MB sorted bf16
  unsigned*       mp_key = (unsigned*)(ws + (2u << 20));                  // 64 KB
  unsigned*       mn_key = (unsigned*)(ws + (2u << 20) + (64u << 10));    // 64 KB
  float*          ce_row = (float*)(ws + (2u << 20) + (128u << 10));      // 64 KB
  int*            ts     = (int*)(ws + (2u << 20) + (192u << 10));        // 64 KB
  int*            cstart = (int*)(ws + (2u << 20) + (256u << 10));        // 65*4 B (pad 1KB)
  int*            hist   = (int*)(ws + (2u << 20) + (257u << 10));        // 256 B
  int*            cursor = (int*)(ws + (2u << 20) + (257u << 10) + 256);  // 256 B
  float*          out    = (float*)d_out;

  // zero hist + cursor in one node
  hipMemsetAsync(hist, 0, 1024, stream);

  hist_kernel<<<64, 256, 0, stream>>>(tgt, hist, mp_key, mn_key);
  prep_kernel<<<1024, 256, 0, stream>>>(x, tgt, hist, cursor, cstart, xs, ts, ce_row);
  mine_kernel<<<64 * 16, 256, 0, stream>>>(xs, ts, cstart, mp_key, mn_key);
  finalize_kernel<<<1, 1024, 0, stream>>>(mp_key, mn_key, ce_row, out);
}